// Round 8
// baseline (179.494 us; speedup 1.0000x reference)
//
#include <hip/hip_runtime.h>
#include <math.h>

// ---------------------------------------------------------------------------
// AmplitudeQuantumNet pipeline.
// R3: conv2 MFMA implicit GEMM (split-bf16). R4: fc MFMA (split-bf16, split-K).
// R5: conv2 TS=40 LDS stride; fc no-LDS fragment loads; front = conv1 + packs.
// R6: quantum wave-per-sample (zero barriers); front 16-B pack stores.
// R7: conv2 waves = (m-half x oc-half): each wave does 32 oc -> A-fragment
//     ds_read_b128 count halved (936->468/block, the measured LDS-pipe floor);
//     B register-resident (36 frags); epilogue via shared [196][64] LDS.
// ---------------------------------------------------------------------------

#define B_SZ 1024

// workspace offsets (in floats)
#define OFF_FCWP   0            // ushort[1605632] fc_w B-fragments (bf16 hi/lo)
#define OFF_W2F    802816       // ushort[36864] conv2 B-fragments (bf16 hi/lo)
#define OFF_SC2    821600      // [64]
#define OFF_SH2    821664      // [64]
#define OFF_H1     821728      // [1024][32][14][14]; reused as fc partials [14][1024][256]
#define OFF_H2P    7244256     // ushort h2hi[1024][3136] ++ h2lo[1024][3136]

#define KSPLIT_FC 14
#define TS 40                   // conv2 LDS pixel stride in ushorts (80 B)

typedef __attribute__((ext_vector_type(8))) short s16x8;
typedef __attribute__((ext_vector_type(4))) float f32x4;

__constant__ float C_COS8[8] = {1.f, 0.70710678f, 0.f, -0.70710678f, -1.f, -0.70710678f, 0.f, 0.70710678f};
__constant__ float C_SIN8[8] = {0.f, 0.70710678f, 1.f, 0.70710678f, 0.f, -0.70710678f, -1.f, -0.70710678f};

__device__ __forceinline__ unsigned short bf16_rne(float f) {
  unsigned u = __float_as_uint(f);
  unsigned r = u + 0x7FFFu + ((u >> 16) & 1u);
  return (unsigned short)(r >> 16);
}
__device__ __forceinline__ int div14(int m) {        // exact for 0 <= m <= 207
  return __float2int_rz((float)m * 0.07142858f);
}

// ------------------- fused front: conv1 + all prep packing -----------------
__global__ __launch_bounds__(256) void fused_front_kernel(
    const float* __restrict__ x, const float* __restrict__ c1w, const float* __restrict__ c1b,
    const float* __restrict__ bn1g, const float* __restrict__ bn1b, const float* __restrict__ bn1m,
    const float* __restrict__ bn1v,
    const float* __restrict__ c2w,
    const float* __restrict__ bn2g, const float* __restrict__ bn2b, const float* __restrict__ bn2m,
    const float* __restrict__ bn2v, const float* __restrict__ c2b,
    const float* __restrict__ fc_w,
    float* __restrict__ ws) {
  const int blk = blockIdx.x, tid = threadIdx.x;
  __shared__ float smem[3136];

  if (blk >= 1024) {
    if (blk < 1280) {
      // ---- fc_w packing: row n staged in LDS, 16-B fragment stores ----
      const int n = blk - 1024;
      const float* src = fc_w + n * 3136;
      for (int i = tid; i < 3136; i += 256) smem[i] = src[i];
      __syncthreads();
      unsigned short* us = (unsigned short*)ws;   // OFF_FCWP == 0
      const int nt = n >> 4, nl = n & 15;
      for (int idx = tid; idx < 784; idx += 256) {
        const int part = (idx >= 392);
        const int rest = idx - part * 392;        // [0,392)
        const int kg = rest >> 2, q = rest & 3;
        s16x8 v;
#pragma unroll
        for (int j = 0; j < 8; ++j) {
          const int k = kg * 32 + q * 8 + j;
          float f = smem[(k & 63) * 49 + (k >> 6)];
          unsigned short hi = bf16_rne(f);
          unsigned short r = hi;
          if (part) r = bf16_rne(f - __uint_as_float((unsigned)hi << 16));
          v[j] = (short)r;
        }
        *(s16x8*)&us[((((kg * 16 + nt) * 2 + part)) << 9) + (q * 16 + nl) * 8] = v;
      }
    } else if (blk < 1424) {
      // ---- conv2 B-fragments ----
      int g = (blk - 1280) * 256 + tid;          // < 36864
      int j = g & 7, L = (g >> 3) & 63, rest = g >> 9;
      int h = rest & 1; rest >>= 1;
      int t = rest % 9, w = rest / 9;
      int occ = w * 16 + (L & 15);
      int ic  = (L >> 4) * 8 + j;
      float v = c2w[occ * 288 + ic * 9 + t];
      unsigned short hi = bf16_rne(v);
      unsigned short res = hi;
      if (h) res = bf16_rne(v - __uint_as_float((unsigned)hi << 16));
      ((unsigned short*)(ws + OFF_W2F))[g] = res;
    } else {
      if (tid < 64) {
        float inv = bn2g[tid] / sqrtf(bn2v[tid] + 1e-5f);
        ws[OFF_SC2 + tid] = inv;
        ws[OFF_SH2 + tid] = c2b[tid] * inv + bn2b[tid] - bn2m[tid] * inv;
      }
    }
    return;
  }

  // -------------------------- conv1 body -----------------------------------
  const int b = blk;
  float (*xs)[32] = (float (*)[32])smem;   // [30][32] padded input
  float* w1s  = smem + 960;                // [288]
  float* sc1s = smem + 1248;               // [32]
  float* sh1s = smem + 1280;               // [32]
  float* h1 = ws + OFF_H1;

  if (tid < 240) ((float4*)smem)[tid] = make_float4(0.f, 0.f, 0.f, 0.f);
  __syncthreads();
  const float* xb = x + b * 784;
  for (int i = tid; i < 784; i += 256) {
    int y = i / 28, c = i - y * 28;
    xs[y + 1][c + 1] = xb[i];
  }
  for (int i = tid; i < 288; i += 256) w1s[i] = c1w[(i & 31) * 9 + (i >> 5)];
  if (tid < 32) {
    float inv = bn1g[tid] / sqrtf(bn1v[tid] + 1e-5f);
    sc1s[tid] = inv;
    sh1s[tid] = c1b[tid] * inv + bn1b[tid] - bn1m[tid] * inv;
  }
  __syncthreads();

  for (int t = tid; t < 448; t += 256) {
    const int oc = t & 31, py = t >> 5;
    float wv[9];
#pragma unroll
    for (int k = 0; k < 9; ++k) wv[k] = w1s[k * 32 + oc];
    float acc0[28], acc1[28];
#pragma unroll
    for (int j = 0; j < 28; ++j) { acc0[j] = 0.f; acc1[j] = 0.f; }
#pragma unroll
    for (int r = 0; r < 4; ++r) {
      const int pr = 2 * py + r;
      float row[32];
#pragma unroll
      for (int q = 0; q < 8; ++q) {
        float4 v = *(const float4*)&xs[pr][4 * q];
        row[4 * q] = v.x; row[4 * q + 1] = v.y; row[4 * q + 2] = v.z; row[4 * q + 3] = v.w;
      }
      if (r <= 2) {
#pragma unroll
        for (int kx = 0; kx < 3; ++kx) {
          const float w = wv[r * 3 + kx];
#pragma unroll
          for (int xx = 0; xx < 28; ++xx) acc0[xx] = fmaf(row[xx + kx], w, acc0[xx]);
        }
      }
      if (r >= 1) {
#pragma unroll
        for (int kx = 0; kx < 3; ++kx) {
          const float w = wv[(r - 1) * 3 + kx];
#pragma unroll
          for (int xx = 0; xx < 28; ++xx) acc1[xx] = fmaf(row[xx + kx], w, acc1[xx]);
        }
      }
    }
    const float sc = sc1s[oc], sh = sh1s[oc];
    float* dst = h1 + b * 6272 + oc * 196 + py * 14;
#pragma unroll
    for (int px = 0; px < 14; ++px) {
      float v0 = fmaxf(fmaf(acc0[2 * px], sc, sh), 0.f);
      float v1 = fmaxf(fmaf(acc0[2 * px + 1], sc, sh), 0.f);
      float v2 = fmaxf(fmaf(acc1[2 * px], sc, sh), 0.f);
      float v3 = fmaxf(fmaf(acc1[2 * px + 1], sc, sh), 0.f);
      dst[px] = fmaxf(fmaxf(v0, v1), fmaxf(v2, v3));
    }
  }
}

// ------------------------- conv2: MFMA implicit GEMM -----------------------
// in: h1[b][32][14][14] fp32; out: h2hi/h2lo[b][49][64] bf16 hi/lo
// Wave = (m-half, oc-half): mh in {0,1} covers mt 0-6 / 7-12; nh covers
// oc 0-31 / 32-63 (2 x 16-oc B-tiles register-resident). A-fragment reads
// amortized over 2 B-tiles -> 468 ds_read_b128 per block (was 936).
__global__ __launch_bounds__(256, 2) void conv2_kernel(
    const float* __restrict__ h1, const float* __restrict__ w2f_f,
    const float* __restrict__ sc2, const float* __restrict__ sh2,
    unsigned short* __restrict__ h2hi, unsigned short* __restrict__ h2lo) {
  const int b = blockIdx.x, tid = threadIdx.x;
  const int lane = tid & 63, w = tid >> 6;
  const int mh = w >> 1, nh = w & 1;

  // phase1: tile_hi/lo [17][16][TS] ushort (2 x 21760 B = 43520)
  // phase2: conv_out [196][64] fp32 = 50176 B (shared, not per-wave)
  __shared__ unsigned char lds_raw[50176];
  unsigned short* tile_hi = (unsigned short*)lds_raw;
  unsigned short* tile_lo = (unsigned short*)(lds_raw + 21760);
  float* conv_out = (float*)lds_raw;

  // ---- B fragments: 9 taps x 2 n-tiles x {hi,lo}, register-resident ----
  const unsigned short* w2f = (const unsigned short*)w2f_f;
  s16x8 bf[9][2][2];
#pragma unroll
  for (int t = 0; t < 9; ++t)
#pragma unroll
    for (int ntl = 0; ntl < 2; ++ntl)
#pragma unroll
      for (int h = 0; h < 2; ++h)
        bf[t][ntl][h] = *(const s16x8*)&w2f[(((((nh * 2 + ntl) * 9 + t) * 2 + h)) << 9) + lane * 8];

  // ---- zero input tile (incl. padding): 43520 B = 2720 float4 ----
  {
    float4* z = (float4*)lds_raw;
    for (int i = tid; i < 2720; i += 256) z[i] = make_float4(0.f, 0.f, 0.f, 0.f);
  }
  __syncthreads();

  // ---- stage h1 -> bf16 hi/lo ----
  if (tid < 196) {
    const int y = div14(tid), x = tid - y * 14;
    const int sp = ((y + 1) * 16 + (x + 1)) * TS;
    const float* src = h1 + b * 6272 + tid;
#pragma unroll
    for (int c = 0; c < 4; ++c) {
      s16x8 hv, lv;
#pragma unroll
      for (int j = 0; j < 8; ++j) {
        float v = src[(c * 8 + j) * 196];
        unsigned short h16 = bf16_rne(v);
        hv[j] = (short)h16;
        lv[j] = (short)bf16_rne(v - __uint_as_float((unsigned)h16 << 16));
      }
      *(s16x8*)&tile_hi[sp + c * 8] = hv;
      *(s16x8*)&tile_lo[sp + c * 8] = lv;
    }
  }
  __syncthreads();

  // ---- main MFMA loop: wave does its 7 (or 6) m-tiles x 32 oc ----
  const int nmt = 7 - mh;            // mh0: 7 tiles (mt 0-6), mh1: 6 (mt 7-12)
  const int mt0 = mh * 7;
  f32x4 acc[7][2];
#pragma unroll
  for (int i = 0; i < 7; ++i) { acc[i][0] = (f32x4){0,0,0,0}; acc[i][1] = (f32x4){0,0,0,0}; }

  const int kg8 = (lane >> 4) * 8;
#pragma unroll
  for (int mi = 0; mi < 7; ++mi) {
    if (mi < nmt) {
      const int m = (mt0 + mi) * 16 + (lane & 15);
      const int y = div14(m), x = m - y * 14;
      const int base = (y * 16 + x) * TS + kg8;
#pragma unroll
      for (int dy = 0; dy < 3; ++dy) {
#pragma unroll
        for (int dx = 0; dx < 3; ++dx) {
          const int off = base + (dy * 16 + dx) * TS;
          s16x8 ah = *(s16x8*)&tile_hi[off];
          s16x8 al = *(s16x8*)&tile_lo[off];
          const int t = dy * 3 + dx;
#pragma unroll
          for (int ntl = 0; ntl < 2; ++ntl) {
            acc[mi][ntl] = __builtin_amdgcn_mfma_f32_16x16x32_bf16(ah, bf[t][ntl][0], acc[mi][ntl], 0, 0, 0);
            acc[mi][ntl] = __builtin_amdgcn_mfma_f32_16x16x32_bf16(ah, bf[t][ntl][1], acc[mi][ntl], 0, 0, 0);
            acc[mi][ntl] = __builtin_amdgcn_mfma_f32_16x16x32_bf16(al, bf[t][ntl][0], acc[mi][ntl], 0, 0, 0);
          }
        }
      }
    }
  }
  __syncthreads();   // all tile reads done before conv_out overwrites LDS

  // ---- epilogue: bn+relu into shared [196][64] ----
#pragma unroll
  for (int mi = 0; mi < 7; ++mi) {
    if (mi < nmt) {
#pragma unroll
      for (int ntl = 0; ntl < 2; ++ntl) {
        const int oc = nh * 32 + ntl * 16 + (lane & 15);
        const float sc = sc2[oc], sh = sh2[oc];
#pragma unroll
        for (int r = 0; r < 4; ++r) {
          const int m = (mt0 + mi) * 16 + (lane >> 4) * 4 + r;
          if (m < 196) conv_out[m * 64 + oc] = fmaxf(fmaf(acc[mi][ntl][r], sc, sh), 0.f);
        }
      }
    }
  }
  __syncthreads();

  // ---- 2x2 maxpool + bf16 hi/lo store [b][49][64] ----
  const int oc = tid & 63;
#pragma unroll
  for (int i = 0; i < 13; ++i) {
    const int ps = i * 4 + (tid >> 6);
    if (ps < 49) {
      const int py = (ps * 37) >> 8, px = ps - py * 7;
      const int m00 = py * 28 + px * 2;
      float v0 = conv_out[m00 * 64 + oc];
      float v1 = conv_out[(m00 + 1) * 64 + oc];
      float v2 = conv_out[(m00 + 14) * 64 + oc];
      float v3 = conv_out[(m00 + 15) * 64 + oc];
      float vm = fmaxf(fmaxf(v0, v1), fmaxf(v2, v3));
      unsigned short hv = bf16_rne(vm);
      const int idx = b * 3136 + ps * 64 + oc;
      h2hi[idx] = hv;
      h2lo[idx] = bf16_rne(vm - __uint_as_float((unsigned)hv << 16));
    }
  }
}

// ------------------------- fc: MFMA GEMM, no LDS, no barriers ---------------
__global__ __launch_bounds__(256) void fc_mfma_kernel(
    const unsigned short* __restrict__ h2hi, const unsigned short* __restrict__ h2lo,
    const unsigned short* __restrict__ Bfrag, float* __restrict__ Part) {
  const int tid = threadIdx.x;
  const int lane = tid & 63, w = tid >> 6;
  const int nt0 = blockIdx.x * 4, z = blockIdx.z;
  const int mrow = blockIdx.y * 64 + w * 16 + (lane & 15);
  const int kg8 = (lane >> 4) * 8;
  const unsigned short* arow_hi = h2hi + mrow * 3136 + kg8;
  const unsigned short* arow_lo = h2lo + mrow * 3136 + kg8;

  f32x4 acc[4];
#pragma unroll
  for (int i = 0; i < 4; ++i) acc[i] = (f32x4){0.f, 0.f, 0.f, 0.f};

#pragma unroll
  for (int c = 0; c < 7; ++c) {
    const int kg = z * 7 + c;
    s16x8 ah = *(const s16x8*)(arow_hi + kg * 32);
    s16x8 al = *(const s16x8*)(arow_lo + kg * 32);
#pragma unroll
    for (int nf = 0; nf < 4; ++nf) {
      const unsigned short* bp = Bfrag + (size_t)((kg * 16 + nt0 + nf) * 2) * 512 + lane * 8;
      s16x8 bh = *(const s16x8*)bp;
      s16x8 bl = *(const s16x8*)(bp + 512);
      acc[nf] = __builtin_amdgcn_mfma_f32_16x16x32_bf16(ah, bh, acc[nf], 0, 0, 0);
      acc[nf] = __builtin_amdgcn_mfma_f32_16x16x32_bf16(ah, bl, acc[nf], 0, 0, 0);
      acc[nf] = __builtin_amdgcn_mfma_f32_16x16x32_bf16(al, bh, acc[nf], 0, 0, 0);
    }
  }

  float* dst = Part + (size_t)z * 262144;
  const int mbase = blockIdx.y * 64 + w * 16 + (lane >> 4) * 4;
  const int nbase = (lane & 15);
#pragma unroll
  for (int nf = 0; nf < 4; ++nf) {
#pragma unroll
    for (int r = 0; r < 4; ++r) {
      dst[(mbase + r) * 256 + (nt0 + nf) * 16 + nbase] = acc[nf][r];
    }
  }
}

// ------------------------- quantum sim + MLP head (wave-per-sample) --------
__global__ __launch_bounds__(64) void quantum_kernel(
    const float* __restrict__ Part, const float* __restrict__ fc_b,
    const float* __restrict__ qp,
    const float* __restrict__ p1w, const float* __restrict__ p1b,
    const float* __restrict__ p2w, const float* __restrict__ p2b,
    const float* __restrict__ p3w, const float* __restrict__ p3b,
    float* __restrict__ out) {
  const int b = blockIdx.x, lane = threadIdx.x;
  __shared__ float csl[160];

  for (int g = lane; g < 80; g += 64) {
    float t = 0.5f * qp[g];
    csl[2 * g] = cosf(t);
    csl[2 * g + 1] = sinf(t);
  }
  __syncthreads();

  float fa[4];
#pragma unroll
  for (int a = 0; a < 4; ++a) {
    const int idx = a * 64 + lane;
    float f = fc_b[idx];
#pragma unroll
    for (int z = 0; z < KSPLIT_FC; ++z) f += Part[z * 262144 + b * 256 + idx];
    fa[a] = tanhf(f);
  }
  float ss = fa[0] * fa[0] + fa[1] * fa[1] + fa[2] * fa[2] + fa[3] * fa[3];
#pragma unroll
  for (int off = 32; off >= 1; off >>= 1) ss += __shfl_xor(ss, off);
  const float inv = 1.0f / sqrtf(ss);

  float re[4], im[4];
#pragma unroll
  for (int a = 0; a < 4; ++a) { re[a] = fa[a] * inv; im[a] = 0.f; }

  float dre[4], dim_[4];
#pragma unroll
  for (int a = 0; a < 4; ++a) {
    const int i = a * 64 + lane;
    const int k8 = (2 * __popc(i & 0xAA) + __popc(i & 0x55)) & 7;
    float dr = C_COS8[k8], di = C_SIN8[k8];
    int par = ((i >> 7) & (i >> 6)) ^ ((i >> 5) & (i >> 4)) ^ ((i >> 3) & (i >> 2)) ^ ((i >> 1) & i)
            ^ ((i >> 6) & (i >> 5)) ^ ((i >> 4) & (i >> 3)) ^ ((i >> 2) & (i >> 1));
    if (par & 1) { dr = -dr; di = -di; }
    dre[a] = dr; dim_[a] = di;
  }

  const float RS = 0.70710678118654752f;

#define H_PAIR(u, v)                                        \
  { float tur = re[u], tui = im[u];                         \
    re[u] = (tur + re[v]) * RS; im[u] = (tui + im[v]) * RS; \
    re[v] = (tur - re[v]) * RS; im[v] = (tui - im[v]) * RS; }
  H_PAIR(0, 2) H_PAIR(1, 3)
  H_PAIR(0, 1) H_PAIR(2, 3)
#pragma unroll
  for (int w = 2; w < 8; ++w) {
    const int m = 1 << (7 - w);
    const float sgn = (lane & m) ? -1.f : 1.f;
#pragma unroll
    for (int a = 0; a < 4; ++a) {
      float pre = __shfl_xor(re[a], m);
      float pim = __shfl_xor(im[a], m);
      re[a] = fmaf(sgn, re[a], pre) * RS;
      im[a] = fmaf(sgn, im[a], pim) * RS;
    }
  }

#define RX_PAIR(u, v, c, s)                                   \
  { float ur = re[u], ui = im[u], wr = re[v], wi = im[v];     \
    re[u] = fmaf(s, wi, c * ur); im[u] = fmaf(-s, wr, c * ui);\
    re[v] = fmaf(s, ui, c * wr); im[v] = fmaf(-s, ur, c * wi); }
  for (int layer = 0; layer < 10; ++layer) {
    const float* cs = &csl[16 * layer];
    { const float c = cs[0], s = cs[1]; RX_PAIR(0, 2, c, s) RX_PAIR(1, 3, c, s) }
    { const float c = cs[2], s = cs[3]; RX_PAIR(0, 1, c, s) RX_PAIR(2, 3, c, s) }
#pragma unroll
    for (int w = 2; w < 8; ++w) {
      const int m = 1 << (7 - w);
      const float c = cs[2 * w], s = cs[2 * w + 1];
#pragma unroll
      for (int a = 0; a < 4; ++a) {
        float pre = __shfl_xor(re[a], m);
        float pim = __shfl_xor(im[a], m);
        float nre = fmaf(s, pim, c * re[a]);
        float nim = fmaf(-s, pre, c * im[a]);
        if (w == 7) {
          float tre = nre * dre[a] - nim * dim_[a];
          nim = fmaf(nre, dim_[a], nim * dre[a]);
          nre = tre;
        }
        re[a] = nre; im[a] = nim;
      }
    }
  }

  float prb[4];
#pragma unroll
  for (int a = 0; a < 4; ++a) prb[a] = re[a] * re[a] + im[a] * im[a];
  float qv[8];
#pragma unroll
  for (int w = 0; w < 8; ++w) {
    float v;
    if (w == 0)      v = prb[0] + prb[1] - prb[2] - prb[3];
    else if (w == 1) v = prb[0] - prb[1] + prb[2] - prb[3];
    else {
      const int m = 1 << (7 - w);
      const float sgn = (lane & m) ? -1.f : 1.f;
      v = sgn * (prb[0] + prb[1] + prb[2] + prb[3]);
    }
#pragma unroll
    for (int off = 32; off >= 1; off >>= 1) v += __shfl_xor(v, off);
    qv[w] = v;
  }

  float z1a = p1b[lane], z1b = p1b[lane + 64];
#pragma unroll
  for (int k = 0; k < 8; ++k) {
    z1a = fmaf(qv[k], p1w[lane * 8 + k], z1a);
    z1b = fmaf(qv[k], p1w[(lane + 64) * 8 + k], z1b);
  }
  z1a = fmaxf(z1a, 0.f); z1b = fmaxf(z1b, 0.f);

  float acc2 = p2b[lane];
  const float* row2 = p2w + lane * 128;
#pragma unroll
  for (int kc = 0; kc < 64; kc += 4) {
    float4 w0 = *(const float4*)&row2[kc];
    float4 w1 = *(const float4*)&row2[64 + kc];
    float wv0[4] = {w0.x, w0.y, w0.z, w0.w};
    float wv1[4] = {w1.x, w1.y, w1.z, w1.w};
#pragma unroll
    for (int j = 0; j < 4; ++j) {
      acc2 = fmaf(__shfl(z1a, kc + j), wv0[j], acc2);
      acc2 = fmaf(__shfl(z1b, kc + j), wv1[j], acc2);
    }
  }
  const float z2 = fmaxf(acc2, 0.f);

#pragma unroll
  for (int n = 0; n < 10; ++n) {
    float p = z2 * p3w[n * 64 + lane];
#pragma unroll
    for (int off = 32; off >= 1; off >>= 1) p += __shfl_xor(p, off);
    if (lane == n) out[b * 10 + n] = p + p3b[n];
  }
}

// ---------------------------------------------------------------------------
extern "C" void kernel_launch(void* const* d_in, const int* in_sizes, int n_in,
                              void* d_out, int out_size, void* d_ws, size_t ws_size,
                              hipStream_t stream) {
  (void)in_sizes; (void)n_in; (void)out_size; (void)ws_size;
  const float* x    = (const float*)d_in[0];
  const float* c1w  = (const float*)d_in[1];
  const float* c1b  = (const float*)d_in[2];
  const float* bn1g = (const float*)d_in[3];
  const float* bn1b = (const float*)d_in[4];
  const float* bn1m = (const float*)d_in[5];
  const float* bn1v = (const float*)d_in[6];
  const float* c2w  = (const float*)d_in[7];
  const float* c2b  = (const float*)d_in[8];
  const float* bn2g = (const float*)d_in[9];
  const float* bn2b = (const float*)d_in[10];
  const float* bn2m = (const float*)d_in[11];
  const float* bn2v = (const float*)d_in[12];
  const float* fc_w = (const float*)d_in[13];
  const float* fc_b = (const float*)d_in[14];
  const float* qp   = (const float*)d_in[15];
  const float* p1w  = (const float*)d_in[16];
  const float* p1b  = (const float*)d_in[17];
  const float* p2w  = (const float*)d_in[18];
  const float* p2b  = (const float*)d_in[19];
  const float* p3w  = (const float*)d_in[20];
  const float* p3b  = (const float*)d_in[21];
  float* ws = (float*)d_ws;
  float* outp = (float*)d_out;

  unsigned short* h2hi = (unsigned short*)(ws + OFF_H2P);
  unsigned short* h2lo = h2hi + 3211264;
  const unsigned short* bfrag = (const unsigned short*)ws;   // OFF_FCWP == 0

  fused_front_kernel<<<1425, 256, 0, stream>>>(x, c1w, c1b, bn1g, bn1b, bn1m, bn1v,
                                               c2w, bn2g, bn2b, bn2m, bn2v, c2b, fc_w, ws);
  conv2_kernel<<<B_SZ, 256, 0, stream>>>(ws + OFF_H1, ws + OFF_W2F, ws + OFF_SC2, ws + OFF_SH2,
                                         h2hi, h2lo);
  // fc partials overwrite H1 (dead after conv2)
  fc_mfma_kernel<<<dim3(4, 16, KSPLIT_FC), 256, 0, stream>>>(h2hi, h2lo, bfrag, ws + OFF_H1);
  quantum_kernel<<<B_SZ, 64, 0, stream>>>(ws + OFF_H1, fc_b, qp, p1w, p1b, p2w, p2b, p3w, p3b, outp);
}

// Round 9
// 179.230 us; speedup vs baseline: 1.0015x; 1.0015x over previous
//
#include <hip/hip_runtime.h>
#include <math.h>

// ---------------------------------------------------------------------------
// AmplitudeQuantumNet pipeline.
// R3/R4: conv2+fc as split-bf16 MFMA GEMMs. R5-R7: LDS stride, no-LDS fc,
// wave-per-sample quantum, conv2 dual-N waves.
// R8: conv1 FUSED into conv2's kernel — conv1 writes pooled outputs directly
//     into the conv2 LDS tile as bf16 hi/lo (bitwise-identical to the old
//     HBM round-trip + restage). Kills 51 MB of h1 traffic + staging phase.
//     Weight packs live in a small prep_pack dispatch.
// ---------------------------------------------------------------------------

#define B_SZ 1024

// workspace offsets (in floats)
#define OFF_FCWP   0            // ushort[1605632] fc_w B-fragments (bf16 hi/lo)
#define OFF_W2F    802816       // ushort[36864] conv2 B-fragments (bf16 hi/lo)
#define OFF_SC2    821600      // [64]
#define OFF_SH2    821664      // [64]
#define OFF_H1     821728      // fc partials [14][1024][256]
#define OFF_H2P    7244256     // ushort h2hi[1024][3136] ++ h2lo[1024][3136]

#define KSPLIT_FC 14
#define TS 40                   // conv2 LDS pixel stride in ushorts (80 B)

typedef __attribute__((ext_vector_type(8))) short s16x8;
typedef __attribute__((ext_vector_type(4))) float f32x4;

__constant__ float C_COS8[8] = {1.f, 0.70710678f, 0.f, -0.70710678f, -1.f, -0.70710678f, 0.f, 0.70710678f};
__constant__ float C_SIN8[8] = {0.f, 0.70710678f, 1.f, 0.70710678f, 0.f, -0.70710678f, -1.f, -0.70710678f};

__device__ __forceinline__ unsigned short bf16_rne(float f) {
  unsigned u = __float_as_uint(f);
  unsigned r = u + 0x7FFFu + ((u >> 16) & 1u);
  return (unsigned short)(r >> 16);
}
__device__ __forceinline__ int div14(int m) {        // exact for 0 <= m <= 207
  return __float2int_rz((float)m * 0.07142858f);
}

// ------------------- prep_pack: weight packing + bn2 fold -------------------
// blocks [0,256): fc_w B-fragment packing (one fc row per block)
// blocks [256,400): conv2 B-fragment packing;  block 400: bn2 fold
__global__ __launch_bounds__(256) void prep_pack_kernel(
    const float* __restrict__ fc_w, const float* __restrict__ c2w,
    const float* __restrict__ bn2g, const float* __restrict__ bn2b, const float* __restrict__ bn2m,
    const float* __restrict__ bn2v, const float* __restrict__ c2b,
    float* __restrict__ ws) {
  const int blk = blockIdx.x, tid = threadIdx.x;
  __shared__ float smem[3136];

  if (blk < 256) {
    const int n = blk;
    const float* src = fc_w + n * 3136;
    for (int i = tid; i < 3136; i += 256) smem[i] = src[i];
    __syncthreads();
    unsigned short* us = (unsigned short*)ws;   // OFF_FCWP == 0
    const int nt = n >> 4, nl = n & 15;
    for (int idx = tid; idx < 784; idx += 256) {
      const int part = (idx >= 392);
      const int rest = idx - part * 392;        // [0,392)
      const int kg = rest >> 2, q = rest & 3;
      s16x8 v;
#pragma unroll
      for (int j = 0; j < 8; ++j) {
        const int k = kg * 32 + q * 8 + j;
        float f = smem[(k & 63) * 49 + (k >> 6)];   // k = s*64+oc -> col oc*49+s
        unsigned short hi = bf16_rne(f);
        unsigned short r = hi;
        if (part) r = bf16_rne(f - __uint_as_float((unsigned)hi << 16));
        v[j] = (short)r;
      }
      *(s16x8*)&us[((((kg * 16 + nt) * 2 + part)) << 9) + (q * 16 + nl) * 8] = v;
    }
  } else if (blk < 400) {
    int g = (blk - 256) * 256 + tid;          // < 36864
    int j = g & 7, L = (g >> 3) & 63, rest = g >> 9;
    int h = rest & 1; rest >>= 1;
    int t = rest % 9, w = rest / 9;
    int occ = w * 16 + (L & 15);
    int ic  = (L >> 4) * 8 + j;
    float v = c2w[occ * 288 + ic * 9 + t];
    unsigned short hi = bf16_rne(v);
    unsigned short res = hi;
    if (h) res = bf16_rne(v - __uint_as_float((unsigned)hi << 16));
    ((unsigned short*)(ws + OFF_W2F))[g] = res;
  } else {
    if (tid < 64) {
      float inv = bn2g[tid] / sqrtf(bn2v[tid] + 1e-5f);
      ws[OFF_SC2 + tid] = inv;
      ws[OFF_SH2 + tid] = c2b[tid] * inv + bn2b[tid] - bn2m[tid] * inv;
    }
  }
}

// ------------------- conv_fused: conv1 -> LDS tile -> conv2 MFMA -----------
// Phase A: conv1+bn+relu+pool computed from x, results written straight into
//          the bf16 hi/lo LDS tile ([17 y][16 x][TS ic]) conv2 consumes.
// Phase B: R7's MFMA loop (wave = m-half x oc-half, 32 oc per wave, B regs).
// out: h2hi/h2lo[b][49][64] bf16 hi/lo.
__global__ __launch_bounds__(256, 2) void conv_fused_kernel(
    const float* __restrict__ x, const float* __restrict__ c1w, const float* __restrict__ c1b,
    const float* __restrict__ bn1g, const float* __restrict__ bn1b, const float* __restrict__ bn1m,
    const float* __restrict__ bn1v,
    const float* __restrict__ w2f_f, const float* __restrict__ sc2, const float* __restrict__ sh2,
    unsigned short* __restrict__ h2hi, unsigned short* __restrict__ h2lo) {
  const int b = blockIdx.x, tid = threadIdx.x;
  const int lane = tid & 63, w = tid >> 6;
  const int mh = w >> 1, nh = w & 1;

  // LDS map: [0,21760) tile_hi  [21760,43520) tile_lo
  //          [43520,47360) xs[30][32]  [47360,48512) w1s[288]
  //          [48512,48640) sc1s  [48640,48768) sh1s
  // phase C (epilogue): conv_out [196][64] fp32 overwrites [0,50176)
  __shared__ unsigned char lds_raw[50176];
  unsigned short* tile_hi = (unsigned short*)lds_raw;
  unsigned short* tile_lo = (unsigned short*)(lds_raw + 21760);
  float* conv_out = (float*)lds_raw;
  float (*xs)[32] = (float (*)[32])(lds_raw + 43520);
  float* w1s  = (float*)(lds_raw + 47360);
  float* sc1s = (float*)(lds_raw + 48512);
  float* sh1s = (float*)(lds_raw + 48640);

  // ---- conv2 B fragments: 9 taps x 2 n-tiles x {hi,lo}, register-resident --
  const unsigned short* w2f = (const unsigned short*)w2f_f;
  s16x8 bf[9][2][2];
#pragma unroll
  for (int t = 0; t < 9; ++t)
#pragma unroll
    for (int ntl = 0; ntl < 2; ++ntl)
#pragma unroll
      for (int h = 0; h < 2; ++h)
        bf[t][ntl][h] = *(const s16x8*)&w2f[(((((nh * 2 + ntl) * 9 + t) * 2 + h)) << 9) + lane * 8];

  // ---- zero tile (incl. padding) + xs: [0,47360) = 2960 float4 ----
  {
    float4* z = (float4*)lds_raw;
    for (int i = tid; i < 2960; i += 256) z[i] = make_float4(0.f, 0.f, 0.f, 0.f);
  }
  __syncthreads();

  // ---- stage x + conv1 weights/bn ----
  const float* xb = x + b * 784;
  for (int i = tid; i < 784; i += 256) {
    int y = i / 28, c = i - y * 28;
    xs[y + 1][c + 1] = xb[i];
  }
  for (int i = tid; i < 288; i += 256) w1s[i] = c1w[(i & 31) * 9 + (i >> 5)];
  if (tid < 32) {
    float inv = bn1g[tid] / sqrtf(bn1v[tid] + 1e-5f);
    sc1s[tid] = inv;
    sh1s[tid] = c1b[tid] * inv + bn1b[tid] - bn1m[tid] * inv;
  }
  __syncthreads();

  // ---- Phase A: conv1+bn+relu+pool -> bf16 hi/lo tile ----
  for (int t = tid; t < 448; t += 256) {
    const int oc = t & 31, py = t >> 5;
    float wv[9];
#pragma unroll
    for (int k = 0; k < 9; ++k) wv[k] = w1s[k * 32 + oc];
    float acc0[28], acc1[28];
#pragma unroll
    for (int j = 0; j < 28; ++j) { acc0[j] = 0.f; acc1[j] = 0.f; }
#pragma unroll
    for (int r = 0; r < 4; ++r) {
      const int pr = 2 * py + r;
      float row[32];
#pragma unroll
      for (int q = 0; q < 8; ++q) {
        float4 v = *(const float4*)&xs[pr][4 * q];
        row[4 * q] = v.x; row[4 * q + 1] = v.y; row[4 * q + 2] = v.z; row[4 * q + 3] = v.w;
      }
      if (r <= 2) {
#pragma unroll
        for (int kx = 0; kx < 3; ++kx) {
          const float ww = wv[r * 3 + kx];
#pragma unroll
          for (int xx = 0; xx < 28; ++xx) acc0[xx] = fmaf(row[xx + kx], ww, acc0[xx]);
        }
      }
      if (r >= 1) {
#pragma unroll
        for (int kx = 0; kx < 3; ++kx) {
          const float ww = wv[(r - 1) * 3 + kx];
#pragma unroll
          for (int xx = 0; xx < 28; ++xx) acc1[xx] = fmaf(row[xx + kx], ww, acc1[xx]);
        }
      }
    }
    const float sc = sc1s[oc], sh = sh1s[oc];
#pragma unroll
    for (int px = 0; px < 14; ++px) {
      float v0 = fmaxf(fmaf(acc0[2 * px], sc, sh), 0.f);
      float v1 = fmaxf(fmaf(acc0[2 * px + 1], sc, sh), 0.f);
      float v2 = fmaxf(fmaf(acc1[2 * px], sc, sh), 0.f);
      float v3 = fmaxf(fmaf(acc1[2 * px + 1], sc, sh), 0.f);
      float vm = fmaxf(fmaxf(v0, v1), fmaxf(v2, v3));
      unsigned short hv = bf16_rne(vm);
      const int sp = ((py + 1) * 16 + (px + 1)) * TS + oc;
      tile_hi[sp] = hv;
      tile_lo[sp] = bf16_rne(vm - __uint_as_float((unsigned)hv << 16));
    }
  }
  __syncthreads();

  // ---- Phase B: MFMA loop (wave: 7/6 m-tiles x 32 oc) ----
  const int nmt = 7 - mh;
  const int mt0 = mh * 7;
  f32x4 acc[7][2];
#pragma unroll
  for (int i = 0; i < 7; ++i) { acc[i][0] = (f32x4){0,0,0,0}; acc[i][1] = (f32x4){0,0,0,0}; }

  const int kg8 = (lane >> 4) * 8;
#pragma unroll
  for (int mi = 0; mi < 7; ++mi) {
    if (mi < nmt) {
      const int m = (mt0 + mi) * 16 + (lane & 15);
      const int y = div14(m), xx_ = m - y * 14;
      const int base = (y * 16 + xx_) * TS + kg8;
#pragma unroll
      for (int dy = 0; dy < 3; ++dy) {
#pragma unroll
        for (int dx = 0; dx < 3; ++dx) {
          const int off = base + (dy * 16 + dx) * TS;
          s16x8 ah = *(s16x8*)&tile_hi[off];
          s16x8 al = *(s16x8*)&tile_lo[off];
          const int t = dy * 3 + dx;
#pragma unroll
          for (int ntl = 0; ntl < 2; ++ntl) {
            acc[mi][ntl] = __builtin_amdgcn_mfma_f32_16x16x32_bf16(ah, bf[t][ntl][0], acc[mi][ntl], 0, 0, 0);
            acc[mi][ntl] = __builtin_amdgcn_mfma_f32_16x16x32_bf16(ah, bf[t][ntl][1], acc[mi][ntl], 0, 0, 0);
            acc[mi][ntl] = __builtin_amdgcn_mfma_f32_16x16x32_bf16(al, bf[t][ntl][0], acc[mi][ntl], 0, 0, 0);
          }
        }
      }
    }
  }
  __syncthreads();   // all tile reads done before conv_out overwrites LDS

  // ---- epilogue: bn+relu into shared [196][64] ----
#pragma unroll
  for (int mi = 0; mi < 7; ++mi) {
    if (mi < nmt) {
#pragma unroll
      for (int ntl = 0; ntl < 2; ++ntl) {
        const int oc = nh * 32 + ntl * 16 + (lane & 15);
        const float sc = sc2[oc], sh = sh2[oc];
#pragma unroll
        for (int r = 0; r < 4; ++r) {
          const int m = (mt0 + mi) * 16 + (lane >> 4) * 4 + r;
          if (m < 196) conv_out[m * 64 + oc] = fmaxf(fmaf(acc[mi][ntl][r], sc, sh), 0.f);
        }
      }
    }
  }
  __syncthreads();

  // ---- 2x2 maxpool + bf16 hi/lo store [b][49][64] ----
  const int oc = tid & 63;
#pragma unroll
  for (int i = 0; i < 13; ++i) {
    const int ps = i * 4 + (tid >> 6);
    if (ps < 49) {
      const int py = (ps * 37) >> 8, px = ps - py * 7;
      const int m00 = py * 28 + px * 2;
      float v0 = conv_out[m00 * 64 + oc];
      float v1 = conv_out[(m00 + 1) * 64 + oc];
      float v2 = conv_out[(m00 + 14) * 64 + oc];
      float v3 = conv_out[(m00 + 15) * 64 + oc];
      float vm = fmaxf(fmaxf(v0, v1), fmaxf(v2, v3));
      unsigned short hv = bf16_rne(vm);
      const int idx = b * 3136 + ps * 64 + oc;
      h2hi[idx] = hv;
      h2lo[idx] = bf16_rne(vm - __uint_as_float((unsigned)hv << 16));
    }
  }
}

// ------------------------- fc: MFMA GEMM, no LDS, no barriers ---------------
__global__ __launch_bounds__(256) void fc_mfma_kernel(
    const unsigned short* __restrict__ h2hi, const unsigned short* __restrict__ h2lo,
    const unsigned short* __restrict__ Bfrag, float* __restrict__ Part) {
  const int tid = threadIdx.x;
  const int lane = tid & 63, w = tid >> 6;
  const int nt0 = blockIdx.x * 4, z = blockIdx.z;
  const int mrow = blockIdx.y * 64 + w * 16 + (lane & 15);
  const int kg8 = (lane >> 4) * 8;
  const unsigned short* arow_hi = h2hi + mrow * 3136 + kg8;
  const unsigned short* arow_lo = h2lo + mrow * 3136 + kg8;

  f32x4 acc[4];
#pragma unroll
  for (int i = 0; i < 4; ++i) acc[i] = (f32x4){0.f, 0.f, 0.f, 0.f};

#pragma unroll
  for (int c = 0; c < 7; ++c) {
    const int kg = z * 7 + c;
    s16x8 ah = *(const s16x8*)(arow_hi + kg * 32);
    s16x8 al = *(const s16x8*)(arow_lo + kg * 32);
#pragma unroll
    for (int nf = 0; nf < 4; ++nf) {
      const unsigned short* bp = Bfrag + (size_t)((kg * 16 + nt0 + nf) * 2) * 512 + lane * 8;
      s16x8 bh = *(const s16x8*)bp;
      s16x8 bl = *(const s16x8*)(bp + 512);
      acc[nf] = __builtin_amdgcn_mfma_f32_16x16x32_bf16(ah, bh, acc[nf], 0, 0, 0);
      acc[nf] = __builtin_amdgcn_mfma_f32_16x16x32_bf16(ah, bl, acc[nf], 0, 0, 0);
      acc[nf] = __builtin_amdgcn_mfma_f32_16x16x32_bf16(al, bh, acc[nf], 0, 0, 0);
    }
  }

  float* dst = Part + (size_t)z * 262144;
  const int mbase = blockIdx.y * 64 + w * 16 + (lane >> 4) * 4;
  const int nbase = (lane & 15);
#pragma unroll
  for (int nf = 0; nf < 4; ++nf) {
#pragma unroll
    for (int r = 0; r < 4; ++r) {
      dst[(mbase + r) * 256 + (nt0 + nf) * 16 + nbase] = acc[nf][r];
    }
  }
}

// ------------------------- quantum sim + MLP head (wave-per-sample) --------
__global__ __launch_bounds__(64) void quantum_kernel(
    const float* __restrict__ Part, const float* __restrict__ fc_b,
    const float* __restrict__ qp,
    const float* __restrict__ p1w, const float* __restrict__ p1b,
    const float* __restrict__ p2w, const float* __restrict__ p2b,
    const float* __restrict__ p3w, const float* __restrict__ p3b,
    float* __restrict__ out) {
  const int b = blockIdx.x, lane = threadIdx.x;
  __shared__ float csl[160];

  for (int g = lane; g < 80; g += 64) {
    float t = 0.5f * qp[g];
    csl[2 * g] = cosf(t);
    csl[2 * g + 1] = sinf(t);
  }
  __syncthreads();

  float fa[4];
#pragma unroll
  for (int a = 0; a < 4; ++a) {
    const int idx = a * 64 + lane;
    float f = fc_b[idx];
#pragma unroll
    for (int z = 0; z < KSPLIT_FC; ++z) f += Part[z * 262144 + b * 256 + idx];
    fa[a] = tanhf(f);
  }
  float ss = fa[0] * fa[0] + fa[1] * fa[1] + fa[2] * fa[2] + fa[3] * fa[3];
#pragma unroll
  for (int off = 32; off >= 1; off >>= 1) ss += __shfl_xor(ss, off);
  const float inv = 1.0f / sqrtf(ss);

  float re[4], im[4];
#pragma unroll
  for (int a = 0; a < 4; ++a) { re[a] = fa[a] * inv; im[a] = 0.f; }

  float dre[4], dim_[4];
#pragma unroll
  for (int a = 0; a < 4; ++a) {
    const int i = a * 64 + lane;
    const int k8 = (2 * __popc(i & 0xAA) + __popc(i & 0x55)) & 7;
    float dr = C_COS8[k8], di = C_SIN8[k8];
    int par = ((i >> 7) & (i >> 6)) ^ ((i >> 5) & (i >> 4)) ^ ((i >> 3) & (i >> 2)) ^ ((i >> 1) & i)
            ^ ((i >> 6) & (i >> 5)) ^ ((i >> 4) & (i >> 3)) ^ ((i >> 2) & (i >> 1));
    if (par & 1) { dr = -dr; di = -di; }
    dre[a] = dr; dim_[a] = di;
  }

  const float RS = 0.70710678118654752f;

#define H_PAIR(u, v)                                        \
  { float tur = re[u], tui = im[u];                         \
    re[u] = (tur + re[v]) * RS; im[u] = (tui + im[v]) * RS; \
    re[v] = (tur - re[v]) * RS; im[v] = (tui - im[v]) * RS; }
  H_PAIR(0, 2) H_PAIR(1, 3)
  H_PAIR(0, 1) H_PAIR(2, 3)
#pragma unroll
  for (int w = 2; w < 8; ++w) {
    const int m = 1 << (7 - w);
    const float sgn = (lane & m) ? -1.f : 1.f;
#pragma unroll
    for (int a = 0; a < 4; ++a) {
      float pre = __shfl_xor(re[a], m);
      float pim = __shfl_xor(im[a], m);
      re[a] = fmaf(sgn, re[a], pre) * RS;
      im[a] = fmaf(sgn, im[a], pim) * RS;
    }
  }

#define RX_PAIR(u, v, c, s)                                   \
  { float ur = re[u], ui = im[u], wr = re[v], wi = im[v];     \
    re[u] = fmaf(s, wi, c * ur); im[u] = fmaf(-s, wr, c * ui);\
    re[v] = fmaf(s, ui, c * wr); im[v] = fmaf(-s, ur, c * wi); }
  for (int layer = 0; layer < 10; ++layer) {
    const float* cs = &csl[16 * layer];
    { const float c = cs[0], s = cs[1]; RX_PAIR(0, 2, c, s) RX_PAIR(1, 3, c, s) }
    { const float c = cs[2], s = cs[3]; RX_PAIR(0, 1, c, s) RX_PAIR(2, 3, c, s) }
#pragma unroll
    for (int w = 2; w < 8; ++w) {
      const int m = 1 << (7 - w);
      const float c = cs[2 * w], s = cs[2 * w + 1];
#pragma unroll
      for (int a = 0; a < 4; ++a) {
        float pre = __shfl_xor(re[a], m);
        float pim = __shfl_xor(im[a], m);
        float nre = fmaf(s, pim, c * re[a]);
        float nim = fmaf(-s, pre, c * im[a]);
        if (w == 7) {
          float tre = nre * dre[a] - nim * dim_[a];
          nim = fmaf(nre, dim_[a], nim * dre[a]);
          nre = tre;
        }
        re[a] = nre; im[a] = nim;
      }
    }
  }

  float prb[4];
#pragma unroll
  for (int a = 0; a < 4; ++a) prb[a] = re[a] * re[a] + im[a] * im[a];
  float qv[8];
#pragma unroll
  for (int w = 0; w < 8; ++w) {
    float v;
    if (w == 0)      v = prb[0] + prb[1] - prb[2] - prb[3];
    else if (w == 1) v = prb[0] - prb[1] + prb[2] - prb[3];
    else {
      const int m = 1 << (7 - w);
      const float sgn = (lane & m) ? -1.f : 1.f;
      v = sgn * (prb[0] + prb[1] + prb[2] + prb[3]);
    }
#pragma unroll
    for (int off = 32; off >= 1; off >>= 1) v += __shfl_xor(v, off);
    qv[w] = v;
  }

  float z1a = p1b[lane], z1b = p1b[lane + 64];
#pragma unroll
  for (int k = 0; k < 8; ++k) {
    z1a = fmaf(qv[k], p1w[lane * 8 + k], z1a);
    z1b = fmaf(qv[k], p1w[(lane + 64) * 8 + k], z1b);
  }
  z1a = fmaxf(z1a, 0.f); z1b = fmaxf(z1b, 0.f);

  float acc2 = p2b[lane];
  const float* row2 = p2w + lane * 128;
#pragma unroll
  for (int kc = 0; kc < 64; kc += 4) {
    float4 w0 = *(const float4*)&row2[kc];
    float4 w1 = *(const float4*)&row2[64 + kc];
    float wv0[4] = {w0.x, w0.y, w0.z, w0.w};
    float wv1[4] = {w1.x, w1.y, w1.z, w1.w};
#pragma unroll
    for (int j = 0; j < 4; ++j) {
      acc2 = fmaf(__shfl(z1a, kc + j), wv0[j], acc2);
      acc2 = fmaf(__shfl(z1b, kc + j), wv1[j], acc2);
    }
  }
  const float z2 = fmaxf(acc2, 0.f);

#pragma unroll
  for (int n = 0; n < 10; ++n) {
    float p = z2 * p3w[n * 64 + lane];
#pragma unroll
    for (int off = 32; off >= 1; off >>= 1) p += __shfl_xor(p, off);
    if (lane == n) out[b * 10 + n] = p + p3b[n];
  }
}

// ---------------------------------------------------------------------------
extern "C" void kernel_launch(void* const* d_in, const int* in_sizes, int n_in,
                              void* d_out, int out_size, void* d_ws, size_t ws_size,
                              hipStream_t stream) {
  (void)in_sizes; (void)n_in; (void)out_size; (void)ws_size;
  const float* x    = (const float*)d_in[0];
  const float* c1w  = (const float*)d_in[1];
  const float* c1b  = (const float*)d_in[2];
  const float* bn1g = (const float*)d_in[3];
  const float* bn1b = (const float*)d_in[4];
  const float* bn1m = (const float*)d_in[5];
  const float* bn1v = (const float*)d_in[6];
  const float* c2w  = (const float*)d_in[7];
  const float* c2b  = (const float*)d_in[8];
  const float* bn2g = (const float*)d_in[9];
  const float* bn2b = (const float*)d_in[10];
  const float* bn2m = (const float*)d_in[11];
  const float* bn2v = (const float*)d_in[12];
  const float* fc_w = (const float*)d_in[13];
  const float* fc_b = (const float*)d_in[14];
  const float* qp   = (const float*)d_in[15];
  const float* p1w  = (const float*)d_in[16];
  const float* p1b  = (const float*)d_in[17];
  const float* p2w  = (const float*)d_in[18];
  const float* p2b  = (const float*)d_in[19];
  const float* p3w  = (const float*)d_in[20];
  const float* p3b  = (const float*)d_in[21];
  float* ws = (float*)d_ws;
  float* outp = (float*)d_out;

  unsigned short* h2hi = (unsigned short*)(ws + OFF_H2P);
  unsigned short* h2lo = h2hi + 3211264;
  const unsigned short* bfrag = (const unsigned short*)ws;   // OFF_FCWP == 0

  prep_pack_kernel<<<401, 256, 0, stream>>>(fc_w, c2w, bn2g, bn2b, bn2m, bn2v, c2b, ws);
  conv_fused_kernel<<<B_SZ, 256, 0, stream>>>(x, c1w, c1b, bn1g, bn1b, bn1m, bn1v,
                                              ws + OFF_W2F, ws + OFF_SC2, ws + OFF_SH2,
                                              h2hi, h2lo);
  fc_mfma_kernel<<<dim3(4, 16, KSPLIT_FC), 256, 0, stream>>>(h2hi, h2lo, bfrag, ws + OFF_H1);
  quantum_kernel<<<B_SZ, 64, 0, stream>>>(ws + OFF_H1, fc_b, qp, p1w, p1b, p2w, p2b, p3w, p3b, outp);
}